// Round 11
// baseline (295.365 us; speedup 1.0000x reference)
//
#include <hip/hip_runtime.h>

// RGCN 2-layer + mean-pool + linear, MI355X (gfx950).
// r9 (2nd resubmit; two consecutive GPU-acquisition timeouts, never measured):
// gemm rebuilt as rt=4 (64-row blocks) with A staged in LDS (24KB,
// chunk-XOR swizzle: slot = chunk ^ (row&7), bijective on [0,24)) so all 4
// waves share A fragments and VGPR stays <=128 (launch_bounds(256,4)).
// Layer-1 stage converts fp32 -> split bf16 hi|lo; layer-2 input X2 is stored
// row-interleaved [hi 192B | lo 192B] by agg3 so both layers share one K-loop.
// scan2 merged into scan3 (10 dispatches total).

#define THREADS 256

typedef __attribute__((ext_vector_type(8))) short short8v;   // 8 x bf16
typedef __attribute__((ext_vector_type(4))) float f32x4;

__device__ __forceinline__ unsigned short f2bf(float f) {
  union { float f; unsigned u; } v; v.f = f;
  unsigned r = v.u + 0x7FFF + ((v.u >> 16) & 1);   // RNE
  return (unsigned short)(r >> 16);
}
__device__ __forceinline__ float bf2f(unsigned short b) {
  union { unsigned u; float f; } v; v.u = ((unsigned)b) << 16;
  return v.f;
}
__device__ __forceinline__ float bits2f(unsigned u) {
  union { unsigned u; float f; } v; v.u = u;
  return v.f;
}
__device__ __forceinline__ unsigned packbf(float a, float b) {
  return ((unsigned)f2bf(b) << 16) | f2bf(a);
}

// ---------- fused prep: packW (288 blocks) + hist (rest) ----------
__global__ __launch_bounds__(256) void k_prep(
    const float* __restrict__ Wrel1, const float* __restrict__ Wroot1,
    const float* __restrict__ Wrel2, const float* __restrict__ Wroot2,
    unsigned short* __restrict__ PBh, unsigned short* __restrict__ PBl,
    const int* __restrict__ ei, const int* __restrict__ et,
    int* __restrict__ cnt, int* __restrict__ rank, int* __restrict__ bucket,
    int E, int N)
{
  int bid = blockIdx.x;
  if (bid < 288) {
    int lay = bid / 144;
    int idx = (bid % 144) * 256 + threadIdx.x;
    const float* Wroot = lay ? Wroot2 : Wroot1;
    const float* Wrel  = lay ? Wrel2  : Wrel1;
    int j    = idx & 7;
    int lane = (idx >> 3) & 63;
    int CT   = (idx >> 9) % 24;
    int ks   = (idx >> 9) / 24;
    int kpos = ks * 32 + (lane >> 4) * 8 + j;
    int k    = lay ? ((kpos % 6) * 16 + kpos / 6) : kpos;  // pi^-1 for layer 2
    int col  = CT * 16 + (lane & 15);
    int m    = col / 96, jj = col % 96;
    float f  = (m == 0) ? Wroot[k * 96 + jj]
                        : Wrel[((size_t)(m - 1) * 96 + k) * 96 + jj];
    unsigned short h = f2bf(f);
    PBh[(size_t)lay * 36864 + idx] = h;
    PBl[(size_t)lay * 36864 + idx] = f2bf(f - bf2f(h));
  } else {
    int e = (bid - 288) * 256 + threadIdx.x;
    if (e >= E) return;
    int b = et[e] * N + ei[E + e];
    bucket[e] = b;
    rank[e] = atomicAdd(&cnt[b], 1);
  }
}

// ---------- scan: per-block inclusive (scan1), then fixup incl. block-sum scan ----------
__global__ __launch_bounds__(256) void k_scan1(int* __restrict__ data, int* __restrict__ blockSums)
{
  __shared__ int sh[256];
  int tid = threadIdx.x;
  size_t base = (size_t)blockIdx.x * 1024 + (size_t)tid * 4;
  int4 v = *(const int4*)(data + base);
  int i0 = v.x, i1 = i0 + v.y, i2 = i1 + v.z, i3 = i2 + v.w;
  int tsum = i3;
  sh[tid] = tsum;
  __syncthreads();
  for (int off = 1; off < 256; off <<= 1) {
    int t = (tid >= off) ? sh[tid - off] : 0;
    __syncthreads();
    sh[tid] += t;
    __syncthreads();
  }
  int excl = sh[tid] - tsum;
  int4 o; o.x = i0 + excl; o.y = i1 + excl; o.z = i2 + excl; o.w = i3 + excl;
  *(int4*)(data + base) = o;
  if (tid == 255) blockSums[blockIdx.x] = sh[255];
}

// scan3: re-scans blockSums locally (nb<=256) and applies this block's offset.
__global__ __launch_bounds__(256) void k_scan3(int* __restrict__ data,
                                               const int* __restrict__ blockSums, int nb)
{
  __shared__ int sh[256];
  int tid = threadIdx.x;
  int v = (tid < nb) ? blockSums[tid] : 0;
  sh[tid] = v;
  __syncthreads();
  for (int off = 1; off < 256; off <<= 1) {
    int t = (tid >= off) ? sh[tid - off] : 0;
    __syncthreads();
    sh[tid] += t;
    __syncthreads();
  }
  int add = (blockIdx.x == 0) ? 0 : sh[blockIdx.x - 1];
  size_t base = (size_t)blockIdx.x * 1024 + (size_t)tid * 4;
  int4 d = *(const int4*)(data + base);
  d.x += add; d.y += add; d.z += add; d.w += add;
  *(int4*)(data + base) = d;
}

// ---------- scatter src ids (u16; N < 65536) ----------
__global__ __launch_bounds__(256) void k_scatter(
    const int* __restrict__ ei, const int* __restrict__ offs,
    const int* __restrict__ rank, const int* __restrict__ bucket,
    unsigned short* __restrict__ payload, int E)
{
  int e = blockIdx.x * THREADS + threadIdx.x;
  if (e >= E) return;
  int b = bucket[e];
  int base = (b == 0) ? 0 : offs[b - 1];
  payload[base + rank[e]] = (unsigned short)ei[e];
}

// ---------- MFMA GEMM: [Yroot fp32 | Hrel bf16](pi-order) = A @ [Wroot|Wrel0..2] ----------
// 64 rows x 384 cols per block; wave wv owns cols [wv*96, wv*96+96).
// A tile staged in LDS (24KB): row = 384B = 24 chunks of 16B; hi half chunks
// [0,12), lo half [12,24); slot = chunk ^ (row&7) (bijective, 2-way banks max).
// F32IN: stage converts fp32 -> split-bf16. Else: input rows already [hi|lo].
template<bool F32IN>
__global__ __launch_bounds__(256, 4) void k_gemm(
    const void* __restrict__ Xin_,
    const unsigned short* __restrict__ PBh, const unsigned short* __restrict__ PBl,
    float* __restrict__ Yroot, unsigned short* __restrict__ Hrel, int nRows)
{
  __shared__ char Als[64 * 384];
  int tid = threadIdx.x;
  int wv = tid >> 6, lane = tid & 63;
  int lr = lane & 15, lq = lane >> 4;
  int r0 = blockIdx.x * 64;

  // ---- stage A tile (1536 dest chunks of 16B; 6 per thread) ----
  if (F32IN) {
    const float* Xf = (const float*)Xin_;
#pragma unroll
    for (int it = 0; it < 6; ++it) {
      int chunkId = it * 256 + tid;
      int row = chunkId / 24, p = chunkId % 24;          // p: fp32 16B chunk
      int grow = r0 + row; if (grow >= nRows) grow = nRows - 1;
      float4 f = *(const float4*)(Xf + (size_t)grow * 96 + p * 4);
      unsigned short h0 = f2bf(f.x), h1 = f2bf(f.y), h2 = f2bf(f.z), h3 = f2bf(f.w);
      unsigned hi0 = ((unsigned)h1 << 16) | h0;
      unsigned hi1 = ((unsigned)h3 << 16) | h2;
      unsigned lo0 = ((unsigned)f2bf(f.y - bf2f(h1)) << 16) | f2bf(f.x - bf2f(h0));
      unsigned lo1 = ((unsigned)f2bf(f.w - bf2f(h3)) << 16) | f2bf(f.z - bf2f(h2));
      int base = row * 384, xo = row & 7, sub = (p & 1) * 8, ch = p >> 1;
      *(uint2*)(&Als[base + (((ch     ) ^ xo) << 4) + sub]) = make_uint2(hi0, hi1);
      *(uint2*)(&Als[base + (((ch + 12) ^ xo) << 4) + sub]) = make_uint2(lo0, lo1);
    }
  } else {
    const char* Xb = (const char*)Xin_;
#pragma unroll
    for (int it = 0; it < 6; ++it) {
      int chunkId = it * 256 + tid;
      int row = chunkId / 24, c = chunkId % 24;
      int grow = r0 + row; if (grow >= nRows) grow = nRows - 1;
      uint4 v = *(const uint4*)(Xb + (size_t)grow * 384 + c * 16);
      *(uint4*)(&Als[row * 384 + ((c ^ (row & 7)) << 4)]) = v;
    }
  }
  __syncthreads();

  f32x4 acc[4][6];
#pragma unroll
  for (int rt = 0; rt < 4; ++rt)
#pragma unroll
    for (int ct = 0; ct < 6; ++ct) acc[rt][ct] = (f32x4){0.f, 0.f, 0.f, 0.f};

  int xo = lr & 7;
#pragma unroll
  for (int ks = 0; ks < 3; ++ks) {
    int chH = (ks * 4 + lq);
#pragma unroll
    for (int ct = 0; ct < 6; ++ct) {
      int CT = wv * 6 + ct;
      size_t boff = ((size_t)(ks * 24 + CT) * 64 + lane) * 8;
      short8v Bh = *(const short8v*)(PBh + boff);
      short8v Bl = *(const short8v*)(PBl + boff);
#pragma unroll
      for (int rt = 0; rt < 4; ++rt) {
        int rowb = (rt * 16 + lr) * 384;
        short8v Ah = *(const short8v*)(&Als[rowb + (((chH     ) ^ xo) << 4)]);
        short8v Al = *(const short8v*)(&Als[rowb + (((chH + 12) ^ xo) << 4)]);
        acc[rt][ct] = __builtin_amdgcn_mfma_f32_16x16x32_bf16(Ah, Bh, acc[rt][ct], 0, 0, 0);
        acc[rt][ct] = __builtin_amdgcn_mfma_f32_16x16x32_bf16(Al, Bh, acc[rt][ct], 0, 0, 0);
        acc[rt][ct] = __builtin_amdgcn_mfma_f32_16x16x32_bf16(Ah, Bl, acc[rt][ct], 0, 0, 0);
      }
    }
  }

  if (wv == 0) {  // root part, fp32, pi-order: lane lr -> positions lr*6..lr*6+5
#pragma unroll
    for (int rt = 0; rt < 4; ++rt)
#pragma unroll
      for (int q = 0; q < 4; ++q) {
        int row = r0 + rt * 16 + lq * 4 + q;
        if (row < nRows) {
          float2* yp = (float2*)(Yroot + (size_t)row * 96 + lr * 6);
          yp[0] = make_float2(acc[rt][0][q], acc[rt][1][q]);
          yp[1] = make_float2(acc[rt][2][q], acc[rt][3][q]);
          yp[2] = make_float2(acc[rt][4][q], acc[rt][5][q]);
        }
      }
  } else {        // relation part, bf16, pi-order
    int r = wv - 1;
#pragma unroll
    for (int rt = 0; rt < 4; ++rt)
#pragma unroll
      for (int q = 0; q < 4; ++q) {
        int row = r0 + rt * 16 + lq * 4 + q;
        if (row < nRows) {
          unsigned* hp = (unsigned*)(Hrel + ((size_t)r * nRows + row) * 96 + lr * 6);
          hp[0] = packbf(acc[rt][0][q], acc[rt][1][q]);
          hp[1] = packbf(acc[rt][2][q], acc[rt][3][q]);
          hp[2] = packbf(acc[rt][4][q], acc[rt][5][q]);
        }
      }
  }
}

// ---------- aggregate (pi-position space): v = root + bias + sum_r mean_r; relu ----------
// outI: next-layer X2, row-interleaved [hi 48 u32 | lo 48 u32] (384B rows).
// outF: final-layer Hout, bf16-packed 48 u32 rows.
__global__ __launch_bounds__(256) void k_agg3(
    const float* __restrict__ Yroot, const unsigned short* __restrict__ Hrel,
    const int* __restrict__ offs, const unsigned short* __restrict__ payload,
    const float* __restrict__ bias,
    unsigned int* outI, unsigned int* outF, int N)
{
  int node = blockIdx.x * 16 + (threadIdx.x >> 4);
  int l = threadIdx.x & 15;
  if (node >= N) return;

  const float2* yp = (const float2*)(Yroot + (size_t)node * 96) + 3 * l;
  float2 y0 = yp[0], y1 = yp[1], y2 = yp[2];
  float v[6];
  v[0] = y0.x + bias[l];       v[1] = y0.y + bias[16 + l];   // pi^-1: pos 6l+i -> ch i*16+l
  v[2] = y1.x + bias[32 + l];  v[3] = y1.y + bias[48 + l];
  v[4] = y2.x + bias[64 + l];  v[5] = y2.y + bias[80 + l];

#pragma unroll
  for (int r = 0; r < 3; ++r) {
    int bkt = r * N + node;
    int s = (bkt == 0) ? 0 : offs[bkt - 1];
    int e = offs[bkt];
    const unsigned int* base = (const unsigned int*)(Hrel + (size_t)r * N * 96);
    float a[6] = {0.f, 0.f, 0.f, 0.f, 0.f, 0.f};
    int t = s;
    for (; t + 3 < e; t += 4) {
      int p0 = payload[t], p1 = payload[t + 1], p2 = payload[t + 2], p3 = payload[t + 3];
      const unsigned int* h0 = base + (size_t)p0 * 48 + 3 * l;
      const unsigned int* h1 = base + (size_t)p1 * 48 + 3 * l;
      const unsigned int* h2 = base + (size_t)p2 * 48 + 3 * l;
      const unsigned int* h3 = base + (size_t)p3 * 48 + 3 * l;
      unsigned u0 = h0[0], u1 = h0[1], u2 = h0[2];
      unsigned w0 = h1[0], w1 = h1[1], w2 = h1[2];
      unsigned x0 = h2[0], x1 = h2[1], x2 = h2[2];
      unsigned z0 = h3[0], z1 = h3[1], z2 = h3[2];
      a[0] += bits2f(u0 << 16); a[1] += bits2f(u0 & 0xFFFF0000u);
      a[2] += bits2f(u1 << 16); a[3] += bits2f(u1 & 0xFFFF0000u);
      a[4] += bits2f(u2 << 16); a[5] += bits2f(u2 & 0xFFFF0000u);
      a[0] += bits2f(w0 << 16); a[1] += bits2f(w0 & 0xFFFF0000u);
      a[2] += bits2f(w1 << 16); a[3] += bits2f(w1 & 0xFFFF0000u);
      a[4] += bits2f(w2 << 16); a[5] += bits2f(w2 & 0xFFFF0000u);
      a[0] += bits2f(x0 << 16); a[1] += bits2f(x0 & 0xFFFF0000u);
      a[2] += bits2f(x1 << 16); a[3] += bits2f(x1 & 0xFFFF0000u);
      a[4] += bits2f(x2 << 16); a[5] += bits2f(x2 & 0xFFFF0000u);
      a[0] += bits2f(z0 << 16); a[1] += bits2f(z0 & 0xFFFF0000u);
      a[2] += bits2f(z1 << 16); a[3] += bits2f(z1 & 0xFFFF0000u);
      a[4] += bits2f(z2 << 16); a[5] += bits2f(z2 & 0xFFFF0000u);
    }
    for (; t < e; ++t) {
      const unsigned int* h0 = base + (size_t)payload[t] * 48 + 3 * l;
      unsigned u0 = h0[0], u1 = h0[1], u2 = h0[2];
      a[0] += bits2f(u0 << 16); a[1] += bits2f(u0 & 0xFFFF0000u);
      a[2] += bits2f(u1 << 16); a[3] += bits2f(u1 & 0xFFFF0000u);
      a[4] += bits2f(u2 << 16); a[5] += bits2f(u2 & 0xFFFF0000u);
    }
    float inv = (e > s) ? 1.0f / (float)(e - s) : 0.0f;
#pragma unroll
    for (int i = 0; i < 6; ++i) v[i] += a[i] * inv;
  }
#pragma unroll
  for (int i = 0; i < 6; ++i) v[i] = fmaxf(v[i], 0.f);

  if (outF) {
    size_t ob = (size_t)node * 48 + 3 * l;
    outF[ob]     = packbf(v[0], v[1]);
    outF[ob + 1] = packbf(v[2], v[3]);
    outF[ob + 2] = packbf(v[4], v[5]);
  } else {
    unsigned short h[6], lo[6];
#pragma unroll
    for (int i = 0; i < 6; ++i) { h[i] = f2bf(v[i]); lo[i] = f2bf(v[i] - bf2f(h[i])); }
    unsigned* xp = outI + (size_t)node * 96;
    xp[3 * l]     = ((unsigned)h[1] << 16) | h[0];
    xp[3 * l + 1] = ((unsigned)h[3] << 16) | h[2];
    xp[3 * l + 2] = ((unsigned)h[5] << 16) | h[4];
    xp[48 + 3 * l]     = ((unsigned)lo[1] << 16) | lo[0];
    xp[48 + 3 * l + 1] = ((unsigned)lo[3] << 16) | lo[2];
    xp[48 + 3 * l + 2] = ((unsigned)lo[5] << 16) | lo[4];
  }
}

// ---------- one block per graph: mean pool (pi-order bf16 rows) + 96->16 linear ----------
__global__ __launch_bounds__(256) void k_poolfinal(
    const unsigned int* __restrict__ H, const int* __restrict__ batch,
    const float* __restrict__ Wlin, const float* __restrict__ blin,
    float* __restrict__ out, int N, int G)
{
  int g = blockIdx.x;
  int tid = threadIdx.x;
  int lo = 0, hi = N;
  while (lo < hi) { int m = (lo + hi) >> 1; if (batch[m] < g) lo = m + 1; else hi = m; }
  int s = lo; hi = N;
  while (lo < hi) { int m = (lo + hi) >> 1; if (batch[m] < g + 1) lo = m + 1; else hi = m; }
  int e = lo;

  int grp = tid >> 4, l = tid & 15;
  float a[6] = {0.f, 0.f, 0.f, 0.f, 0.f, 0.f};
  for (int i = s + grp; i < e; i += 16) {
    const unsigned int* hp = H + (size_t)i * 48 + 3 * l;
    unsigned u0 = hp[0], u1 = hp[1], u2 = hp[2];
    a[0] += bits2f(u0 << 16); a[1] += bits2f(u0 & 0xFFFF0000u);
    a[2] += bits2f(u1 << 16); a[3] += bits2f(u1 & 0xFFFF0000u);
    a[4] += bits2f(u2 << 16); a[5] += bits2f(u2 & 0xFFFF0000u);
  }
  __shared__ float sh[16][96];
  __shared__ float pooled[96];
#pragma unroll
  for (int i = 0; i < 6; ++i) sh[grp][6 * l + i] = a[i];
  __syncthreads();
  if (tid < 96) {
    float t = 0.f;
#pragma unroll
    for (int j = 0; j < 16; ++j) t += sh[j][tid];
    float inv = (e > s) ? 1.0f / (float)(e - s) : 0.0f;
    pooled[tid] = t * inv;
  }
  __syncthreads();
  if (tid < 16) {
    float acc = blin[tid];
#pragma unroll
    for (int k = 0; k < 96; ++k)   // pooled pos k = true channel (k%6)*16+k/6
      acc = fmaf(pooled[k], Wlin[((k % 6) * 16 + k / 6) * 16 + tid], acc);
    out[(size_t)g * 16 + tid] = acc;
  }
}

extern "C" void kernel_launch(void* const* d_in, const int* in_sizes, int n_in,
                              void* d_out, int out_size, void* d_ws, size_t ws_size,
                              hipStream_t stream)
{
  const float* x      = (const float*)d_in[0];
  const int*   ei     = (const int*)d_in[1];
  const int*   et     = (const int*)d_in[2];
  const int*   batch  = (const int*)d_in[3];
  const float* Wrel1  = (const float*)d_in[4];
  const float* Wroot1 = (const float*)d_in[5];
  const float* b1     = (const float*)d_in[6];
  const float* Wrel2  = (const float*)d_in[7];
  const float* Wroot2 = (const float*)d_in[8];
  const float* b2     = (const float*)d_in[9];
  const float* Wlin   = (const float*)d_in[10];
  const float* blin   = (const float*)d_in[11];
  float* out = (float*)d_out;
  (void)n_in; (void)ws_size;

  int N = in_sizes[0] / 96;   // 50000 (< 65536: u16 payload assumption)
  int E = in_sizes[1] / 2;
  int G = out_size / 16;
  int NB = 3 * N;
  int nb1 = (NB + 1023) / 1024;
  int SCAN = nb1 * 1024;

  char* w = (char*)d_ws;
  size_t o = 0;
  auto carve = [&](size_t bytes) -> char* {
    char* p = w + o;
    o = (o + bytes + 255) & ~(size_t)255;
    return p;
  };
  float*          Yroot = (float*)carve((size_t)N * 96 * 4);                 // 19.2 MB
  unsigned short* Hrel  = (unsigned short*)carve((size_t)3 * N * 96 * 2);    // 28.8 MB
  unsigned int*   X2    = (unsigned int*)carve((size_t)N * 96 * 4);          // 19.2 MB [hi|lo]
  unsigned int*   Hout  = (unsigned int*)carve((size_t)N * 48 * 4);          // 9.6 MB
  unsigned short* PBh   = (unsigned short*)carve((size_t)2 * 36864 * 2);
  unsigned short* PBl   = (unsigned short*)carve((size_t)2 * 36864 * 2);
  int*            offs  = (int*)carve((size_t)SCAN * 4);
  int*            blockSums = (int*)carve(256 * 4);
  int*            rank  = (int*)carve((size_t)E * 4);
  int*            bucket= (int*)carve((size_t)E * 4);
  unsigned short* payload = (unsigned short*)carve((size_t)E * 2);

  hipMemsetAsync(offs, 0, (size_t)SCAN * 4, stream);

  int histBlocks = (E + THREADS - 1) / THREADS;
  k_prep<<<288 + histBlocks, THREADS, 0, stream>>>(
      Wrel1, Wroot1, Wrel2, Wroot2, PBh, PBl, ei, et, offs, rank, bucket, E, N);
  k_scan1<<<nb1, THREADS, 0, stream>>>(offs, blockSums);
  k_scan3<<<nb1, THREADS, 0, stream>>>(offs, blockSums, nb1);
  k_scatter<<<histBlocks, THREADS, 0, stream>>>(ei, offs, rank, bucket, payload, E);

  int gg = (N + 63) / 64;
  int ag = (N + 15) / 16;

  // layer 1 (fp32 input; stage converts to split-bf16 in LDS)
  k_gemm<true><<<gg, THREADS, 0, stream>>>(x, PBh, PBl, Yroot, Hrel, N);
  k_agg3<<<ag, THREADS, 0, stream>>>(Yroot, Hrel, offs, payload, b1,
                                     X2, nullptr, N);
  // layer 2 (X2 rows already [hi|lo] interleaved)
  k_gemm<false><<<gg, THREADS, 0, stream>>>(X2, PBh + 36864, PBl + 36864, Yroot, Hrel, N);
  k_agg3<<<ag, THREADS, 0, stream>>>(Yroot, Hrel, offs, payload, b2,
                                     nullptr, Hout, N);

  k_poolfinal<<<G, THREADS, 0, stream>>>(Hout, batch, Wlin, blin, out, N, G);
}